// Round 3
// baseline (88.532 us; speedup 1.0000x reference)
//
#include <hip/hip_runtime.h>

#define HW    262144      // 512*512
#define HW4   65536       // HW/4
#define NPIX  2097152     // 8*512*512
#define CNEW  21
#define COLD  16

// ---------- pass 1: bitmask of classes present in masks ----------
__global__ __launch_bounds__(256)
void lgod_present_scan(const int4* __restrict__ m4,
                       unsigned int* __restrict__ pm) {
    const int p = blockIdx.x * blockDim.x + threadIdx.x;   // 0 .. NPIX/4-1
    int4 v = m4[p];
    unsigned int local = 0;
    if (v.x >= 1 && v.x < CNEW) local |= (1u << v.x);
    if (v.y >= 1 && v.y < CNEW) local |= (1u << v.y);
    if (v.z >= 1 && v.z < CNEW) local |= (1u << v.z);
    if (v.w >= 1 && v.w < CNEW) local |= (1u << v.w);
    #pragma unroll
    for (int off = 32; off; off >>= 1) local |= __shfl_down(local, off);
    __shared__ unsigned int sm;
    if (threadIdx.x == 0) sm = 0;
    __syncthreads();
    if ((threadIdx.x & 63) == 0 && local) atomicOr(&sm, local);
    __syncthreads();
    if (threadIdx.x == 0 && sm) atomicOr(pm, sm);
}

// ---------- pass 2: fused loss, full-ILP variant ----------
// All 37 float4 loads issued before any compute: one wave keeps 37 KB in
// flight (latency-BW product is ~9 KB/CU), so 2 waves/SIMD saturate memory.
__global__ __launch_bounds__(256)
void lgod_main(const float4* __restrict__ inp4,   // [8,21,HW/4]
               const float4* __restrict__ tgt4,   // [8,16,HW/4]
               const int4*   __restrict__ masks4, // [NPIX/4]
               const unsigned int* __restrict__ pm_p,
               double* __restrict__ accum) {
    const unsigned int pm = *pm_p;
    const int t   = blockIdx.x * blockDim.x + threadIdx.x;  // 0 .. NPIX/4-1
    const int b   = t >> 16;
    const int hw4 = t & (HW4 - 1);
    const float4* ip = inp4 + (size_t)b * CNEW * HW4 + hw4;
    const float4* tp = tgt4 + (size_t)b * COLD * HW4 + hw4;

    // ---- issue ALL loads up front ----
    float4 tv[COLD];
    float4 iv[CNEW];
    #pragma unroll
    for (int c = 0; c < COLD; ++c) tv[c] = tp[(size_t)c * HW4];
    #pragma unroll
    for (int c = 0; c < CNEW; ++c) iv[c] = ip[(size_t)c * HW4];
    const int4 mv = masks4[t];
    __builtin_amdgcn_sched_barrier(0);   // keep loads clustered above compute

    int ma[4] = {mv.x, mv.y, mv.z, mv.w};
    int mm[4];
    #pragma unroll
    for (int j = 0; j < 4; ++j)
        mm[j] = (ma[j] == 0 || ma[j] == 255) ? 0 : ma[j];

    float se[4] = {0,0,0,0};   // sum exp(inputs)
    float st[4] = {0,0,0,0};   // sum exp(targets)
    float P[4]  = {0,0,0,0};   // sum_absent in[c]*exp(t[c])
    float Q[4]  = {0,0,0,0};   // sum_absent exp(t[c])
    float t0e[4];              // exp(t[0])
    float vm[4];               // in[mm]

    #pragma unroll
    for (int c = 0; c < COLD; ++c) {
        float ia[4] = {iv[c].x, iv[c].y, iv[c].z, iv[c].w};
        float ta[4] = {tv[c].x, tv[c].y, tv[c].z, tv[c].w};
        const bool absent = (c >= 1) && !((pm >> c) & 1u);  // wave-uniform
        #pragma unroll
        for (int j = 0; j < 4; ++j) {
            float e = __expf(ta[j]);
            st[j] += e;
            if (c == 0) t0e[j] = e;
            if (absent) { P[j] += ia[j] * e; Q[j] += e; }
            se[j] += __expf(ia[j]);
            if (c == 0) vm[j] = ia[j];
            else        vm[j] = (c == mm[j]) ? ia[j] : vm[j];
        }
    }
    #pragma unroll
    for (int c = COLD; c < CNEW; ++c) {
        float ia[4] = {iv[c].x, iv[c].y, iv[c].z, iv[c].w};
        #pragma unroll
        for (int j = 0; j < 4; ++j) {
            se[j] += __expf(ia[j]);
            vm[j] = (c == mm[j]) ? ia[j] : vm[j];
        }
    }

    float acc = 0.f;
    #pragma unroll
    for (int j = 0; j < 4; ++j) {
        float lse = __logf(se[j]);
        float inv = 1.0f / st[j];
        float S = 0.f;
        if (ma[j] < CNEW || ma[j] == 255)     // valid label -> out[mm]*labels0
            S = (vm[j] - lse) * t0e[j];
        S += P[j] - lse * Q[j];               // absent-class channels (0 if none)
        acc += S * inv;
    }

    // wave reduce -> block reduce -> one double atomic per block
    #pragma unroll
    for (int off = 32; off; off >>= 1) acc += __shfl_down(acc, off);
    __shared__ float warp_s[4];
    const int wid = threadIdx.x >> 6;
    if ((threadIdx.x & 63) == 0) warp_s[wid] = acc;
    __syncthreads();
    if (threadIdx.x == 0) {
        float tot = warp_s[0] + warp_s[1] + warp_s[2] + warp_s[3];
        atomicAdd(accum, (double)tot);
    }
}

// ---------- pass 3: finalize scalar ----------
__global__ void lgod_finalize(const double* __restrict__ accum,
                              float* __restrict__ out) {
    out[0] = (float)(-accum[0] / ((double)CNEW * (double)NPIX));
}

extern "C" void kernel_launch(void* const* d_in, const int* in_sizes, int n_in,
                              void* d_out, int out_size, void* d_ws, size_t ws_size,
                              hipStream_t stream) {
    const float4* inp4   = (const float4*)d_in[0];
    const float4* tgt4   = (const float4*)d_in[1];
    const int*    masks  = (const int*)d_in[2];
    float* out = (float*)d_out;

    double* accum    = (double*)d_ws;                       // 8 B
    unsigned int* pm = (unsigned int*)((char*)d_ws + 8);    // 4 B

    hipMemsetAsync(d_ws, 0, 16, stream);
    lgod_present_scan<<<NPIX / 4 / 256, 256, 0, stream>>>((const int4*)masks, pm);
    lgod_main<<<NPIX / 4 / 256, 256, 0, stream>>>(inp4, (const float4*)d_in[1],
                                                  (const int4*)masks, pm, accum);
    lgod_finalize<<<1, 1, 0, stream>>>(accum, out);
    (void)out_size; (void)ws_size; (void)n_in; (void)in_sizes;
}

// Round 4
// 68.438 us; speedup vs baseline: 1.2936x; 1.2936x over previous
//
#include <hip/hip_runtime.h>

#define HW    262144      // 512*512
#define HW4   65536       // HW/4
#define NPIX  2097152     // 8*512*512
#define NG    (NPIX / 4)  // float4 pixel-groups
#define CNEW  21
#define COLD  16

// ---------- pass 1: bitmask of classes present in masks ----------
__global__ void lgod_present_scan(const int* __restrict__ masks,
                                  unsigned int* __restrict__ pm) {
    unsigned int local = 0;
    const int4* m4 = (const int4*)masks;
    const int stride = gridDim.x * blockDim.x;
    for (int p = blockIdx.x * blockDim.x + threadIdx.x; p < NG; p += stride) {
        int4 v = m4[p];
        if (v.x >= 1 && v.x < CNEW) local |= (1u << v.x);
        if (v.y >= 1 && v.y < CNEW) local |= (1u << v.y);
        if (v.z >= 1 && v.z < CNEW) local |= (1u << v.z);
        if (v.w >= 1 && v.w < CNEW) local |= (1u << v.w);
    }
    #pragma unroll
    for (int off = 32; off; off >>= 1) local |= __shfl_down(local, off);
    __shared__ unsigned int sm;
    if (threadIdx.x == 0) sm = 0;
    __syncthreads();
    if ((threadIdx.x & 63) == 0 && local) atomicOr(&sm, local);
    __syncthreads();
    if (threadIdx.x == 0 && sm) atomicOr(pm, sm);
}

// ---------- pass 2: fused loss — grid-stride float4 streaming loop ----------
// Plain loop, no sched_barrier: let the compiler software-pipeline the
// 37-stream float4 reads across iterations (copy-ubench style).
__global__ __launch_bounds__(256)
void lgod_main(const float4* __restrict__ inp4,   // [8,21,HW/4]
               const float4* __restrict__ tgt4,   // [8,16,HW/4]
               const int4*   __restrict__ masks4, // [NG]
               const unsigned int* __restrict__ pm_p,
               double* __restrict__ accum) {
    const unsigned int pm = *pm_p;
    const int stride = gridDim.x * blockDim.x;

    float acc = 0.f;
    for (int t = blockIdx.x * blockDim.x + threadIdx.x; t < NG; t += stride) {
        const int b   = t >> 16;
        const int hw4 = t & (HW4 - 1);
        const float4* ip = inp4 + (size_t)b * CNEW * HW4 + hw4;
        const float4* tp = tgt4 + (size_t)b * COLD * HW4 + hw4;

        const int4 mv = masks4[t];
        int ma[4] = {mv.x, mv.y, mv.z, mv.w};
        int mm[4];
        #pragma unroll
        for (int j = 0; j < 4; ++j)
            mm[j] = (ma[j] == 0 || ma[j] == 255) ? 0 : ma[j];

        float se[4] = {0,0,0,0};   // sum exp(inputs)
        float st[4] = {0,0,0,0};   // sum exp(targets)
        float P[4]  = {0,0,0,0};   // sum_absent in[c]*exp(t[c])
        float Q[4]  = {0,0,0,0};   // sum_absent exp(t[c])
        float t0e[4];              // exp(t[0])
        float vm[4];               // in[mm]

        #pragma unroll
        for (int c = 0; c < COLD; ++c) {
            float4 iv = ip[(size_t)c * HW4];
            float4 tv = tp[(size_t)c * HW4];
            float ia[4] = {iv.x, iv.y, iv.z, iv.w};
            float ta[4] = {tv.x, tv.y, tv.z, tv.w};
            const bool absent = (c >= 1) && !((pm >> c) & 1u);  // wave-uniform
            #pragma unroll
            for (int j = 0; j < 4; ++j) {
                float e = __expf(ta[j]);
                st[j] += e;
                if (c == 0) t0e[j] = e;
                if (absent) { P[j] += ia[j] * e; Q[j] += e; }
                se[j] += __expf(ia[j]);
                if (c == 0) vm[j] = ia[j];
                else        vm[j] = (c == mm[j]) ? ia[j] : vm[j];
            }
        }
        #pragma unroll
        for (int c = COLD; c < CNEW; ++c) {
            float4 iv = ip[(size_t)c * HW4];
            float ia[4] = {iv.x, iv.y, iv.z, iv.w};
            #pragma unroll
            for (int j = 0; j < 4; ++j) {
                se[j] += __expf(ia[j]);
                vm[j] = (c == mm[j]) ? ia[j] : vm[j];
            }
        }

        #pragma unroll
        for (int j = 0; j < 4; ++j) {
            float lse = __logf(se[j]);
            float inv = 1.0f / st[j];
            float S = 0.f;
            if (ma[j] < CNEW || ma[j] == 255)     // valid label -> out[mm]*labels0
                S = (vm[j] - lse) * t0e[j];
            S += P[j] - lse * Q[j];               // absent-class channels
            acc += S * inv;
        }
    }

    // wave reduce -> block reduce -> one double atomic per block
    #pragma unroll
    for (int off = 32; off; off >>= 1) acc += __shfl_down(acc, off);
    __shared__ float warp_s[4];
    const int wid = threadIdx.x >> 6;
    if ((threadIdx.x & 63) == 0) warp_s[wid] = acc;
    __syncthreads();
    if (threadIdx.x == 0) {
        float tot = warp_s[0] + warp_s[1] + warp_s[2] + warp_s[3];
        atomicAdd(accum, (double)tot);
    }
}

// ---------- pass 3: finalize scalar ----------
__global__ void lgod_finalize(const double* __restrict__ accum,
                              float* __restrict__ out) {
    out[0] = (float)(-accum[0] / ((double)CNEW * (double)NPIX));
}

extern "C" void kernel_launch(void* const* d_in, const int* in_sizes, int n_in,
                              void* d_out, int out_size, void* d_ws, size_t ws_size,
                              hipStream_t stream) {
    const float4* inp4   = (const float4*)d_in[0];
    const float4* tgt4   = (const float4*)d_in[1];
    const int*    masks  = (const int*)d_in[2];
    float* out = (float*)d_out;

    double* accum    = (double*)d_ws;                       // 8 B
    unsigned int* pm = (unsigned int*)((char*)d_ws + 8);    // 4 B

    hipMemsetAsync(d_ws, 0, 16, stream);
    lgod_present_scan<<<256, 256, 0, stream>>>(masks, pm);
    lgod_main<<<1024, 256, 0, stream>>>(inp4, (const float4*)d_in[1],
                                        (const int4*)masks, pm, accum);
    lgod_finalize<<<1, 1, 0, stream>>>(accum, out);
    (void)out_size; (void)ws_size; (void)n_in; (void)in_sizes;
}